// Round 3
// baseline (763.325 us; speedup 1.0000x reference)
//
#include <hip/hip_runtime.h>
#include <math.h>

#define N_ROWS 16384
#define C_CODES 8192
#define DIM 512
#define I_OFS (N_ROWS * DIM)          // 8,388,608
#define D_OFS (I_OFS + N_ROWS)       // 8,404,992

typedef __bf16 bf16;
typedef bf16 bf16x8 __attribute__((ext_vector_type(8)));
typedef float f32x4 __attribute__((ext_vector_type(4)));

// ---- async global->LDS, 16B per lane. LDS dest must be wave-uniform base + lane*16.
__device__ __forceinline__ void gload16(void* lds, const void* g) {
  __builtin_amdgcn_global_load_lds((__attribute__((address_space(1))) void*)(g),
                                   (__attribute__((address_space(3))) void*)(lds), 16, 0, 0);
}

// ---- Kernel 1: normalize embed rows -> en (fp32) + enb (bf16). One wave per row.
__global__ void norm_embed(const float* __restrict__ embed, float* __restrict__ en,
                           bf16* __restrict__ enb) {
  int wave = threadIdx.x >> 6, lane = threadIdx.x & 63;
  int row = blockIdx.x * 4 + wave;
  const float* src = embed + (size_t)row * DIM;
  float4 v0 = ((const float4*)src)[lane * 2];
  float4 v1 = ((const float4*)src)[lane * 2 + 1];
  float s = v0.x * v0.x + v0.y * v0.y + v0.z * v0.z + v0.w * v0.w +
            v1.x * v1.x + v1.y * v1.y + v1.z * v1.z + v1.w * v1.w;
  for (int m = 1; m < 64; m <<= 1) s += __shfl_xor(s, m, 64);
  float nrm = fmaxf(sqrtf(s), 1e-12f);
  float4 o0, o1;
  o0.x = v0.x / nrm; o0.y = v0.y / nrm; o0.z = v0.z / nrm; o0.w = v0.w / nrm;
  o1.x = v1.x / nrm; o1.y = v1.y / nrm; o1.z = v1.z / nrm; o1.w = v1.w / nrm;
  float* dst = en + (size_t)row * DIM;
  ((float4*)dst)[lane * 2] = o0;
  ((float4*)dst)[lane * 2 + 1] = o1;
  bf16x8 b;
  b[0] = (bf16)o0.x; b[1] = (bf16)o0.y; b[2] = (bf16)o0.z; b[3] = (bf16)o0.w;
  b[4] = (bf16)o1.x; b[5] = (bf16)o1.y; b[6] = (bf16)o1.z; b[7] = (bf16)o1.w;
  *(bf16x8*)(enb + (size_t)row * DIM + lane * 8) = b;
}

// ---- Kernel 2: normalize x rows -> xnb (bf16) + xnorm (fp32 norms). One wave per row.
__global__ void norm_x(const float* __restrict__ x, bf16* __restrict__ xnb,
                       float* __restrict__ xnorm) {
  int wave = threadIdx.x >> 6, lane = threadIdx.x & 63;
  int row = blockIdx.x * 4 + wave;
  const float* src = x + (size_t)row * DIM;
  float4 v0 = ((const float4*)src)[lane * 2];
  float4 v1 = ((const float4*)src)[lane * 2 + 1];
  float s = v0.x * v0.x + v0.y * v0.y + v0.z * v0.z + v0.w * v0.w +
            v1.x * v1.x + v1.y * v1.y + v1.z * v1.z + v1.w * v1.w;
  for (int m = 1; m < 64; m <<= 1) s += __shfl_xor(s, m, 64);
  float nrm = fmaxf(sqrtf(s), 1e-12f);
  if (lane == 0) xnorm[row] = nrm;
  bf16x8 b;
  b[0] = (bf16)(v0.x / nrm); b[1] = (bf16)(v0.y / nrm);
  b[2] = (bf16)(v0.z / nrm); b[3] = (bf16)(v0.w / nrm);
  b[4] = (bf16)(v1.x / nrm); b[5] = (bf16)(v1.y / nrm);
  b[6] = (bf16)(v1.z / nrm); b[7] = (bf16)(v1.w / nrm);
  *(bf16x8*)(xnb + (size_t)row * DIM + lane * 8) = b;
}

// ---- Kernel 3: dist = xn @ en^T. 256x256 tile, BK=64, 8 waves, 8-phase schedule
// (T2 swizzle + T3/T4 counted vmcnt + T5 setprio), per m201 template.
// LDS: [dbuf 2][op A/B][half 2][128 rows x 64 k bf16] = 128 KiB, double-buffered.
// Swizzle: LDS linear dest + inverse-swizzled GLOBAL source + swizzled ds_read:
//   byte_in_row ^= ((row & 7) << 4)   (involution, 16B-granular)
// Stage-slot placement (race-safe, >=1 barrier after region's last read):
//   region last ds_read: B = ph1, A = ph2.
//   ph0 -> slot 4t+7 (A1 of t+1, OTHER buffer: always safe)
//   ph1 -> none
//   ph2 -> slot 4t+8 (B0 of t+2, cur buf: after end-of-ph1 barrier)
//   ph3 -> slots 4t+9 (B1), 4t+10 (A0, after end-of-ph2 barrier)

#define SB __builtin_amdgcn_sched_barrier(0)
#define BARR __builtin_amdgcn_s_barrier()
#define WLG do { asm volatile("s_waitcnt lgkmcnt(0)" ::: "memory"); SB; } while (0)

__device__ __forceinline__ void stage_hh(char* sm, const bf16* pA, const bf16* pB,
                                         int tid, int j) {
  // half-tile stream: j = 4*tau + hh, hh: 0=B0,1=B1,2=A0,3=A1; dest dbuf = tau&1
  if (j >= 32) return;
  int tau = j >> 2, hh = j & 3, d = tau & 1;
  const bf16* p = (hh >= 2) ? pA : pB;
  int half = hh & 1;
  int opb = (hh >= 2) ? 0 : 32768;
  size_t go = (size_t)(half * 128) * DIM + (size_t)tau * 64;
  char* db = sm + d * 65536 + opb + half * 16384 + tid * 16;
  gload16(db, p + go);                              // rows 0..63 of the half
  gload16(db + 8192, p + go + (size_t)64 * DIM);    // rows 64..127
}

__global__ __launch_bounds__(512, 1) void gemm_dist(
    const bf16* __restrict__ xnb, const bf16* __restrict__ enb,
    float* __restrict__ dist, float* __restrict__ tilemax) {
  __shared__ char sm[131072];

  int tid = threadIdx.x;
  int bid = blockIdx.x;
  // XCD-aware bijective swizzle: nwg = 2048, 8 XCDs, 256 wgs per XCD chunk
  int swz = (bid & 7) * 256 + (bid >> 3);
  int rb = swz >> 5, cb = swz & 31;     // 64 row blocks x 32 col blocks
  int rowBase = rb * 256, colBase = cb * 256;
  int wave = tid >> 6, lane = tid & 63;
  int wr = wave >> 2, wc = wave & 3;    // 2 x 4 wave grid; wave owns 128x64 out
  int row16 = lane & 15, quad = lane >> 4;

  // staging source: thread t loads rows (t>>3) + 64*round, pre-swizzled col
  int trow = tid >> 3;
  int kel = ((tid & 7) ^ (trow & 7)) << 3;  // element offset (swz^-1 of linear dest)
  const bf16* pA = xnb + (size_t)(rowBase + trow) * DIM + kel;
  const bf16* pB = enb + (size_t)(colBase + trow) * DIM + kel;

  // swizzled ds_read offsets within a [128][64]bf16 half (128B rows)
  int msk = (row16 & 7) << 4;
  int o0 = row16 * 128 + ((quad << 4) ^ msk);           // k 0..31 octet
  int o1 = row16 * 128 + (((quad << 4) | 64) ^ msk);    // k 32..63 octet

  f32x4 acc[8][4];
  f32x4 zero = {0.f, 0.f, 0.f, 0.f};
#pragma unroll
  for (int i = 0; i < 8; ++i)
#pragma unroll
    for (int j = 0; j < 4; ++j) acc[i][j] = zero;

  bf16x8 a[4][2], b01[2][2], b23[2][2];

#define LDA(mh) do { _Pragma("unroll") for (int m = 0; m < 4; ++m) { \
      a[m][0] = *(const bf16x8*)(aB + (mh) * 8192 + m * 2048 + o0); \
      a[m][1] = *(const bf16x8*)(aB + (mh) * 8192 + m * 2048 + o1); } } while (0)
#define LDB(breg, pr) do { _Pragma("unroll") for (int n = 0; n < 2; ++n) { \
      breg[n][0] = *(const bf16x8*)(bB + ((pr) * 2 + n) * 2048 + o0); \
      breg[n][1] = *(const bf16x8*)(bB + ((pr) * 2 + n) * 2048 + o1); } } while (0)
#define MF(mh, pr, breg) do { _Pragma("unroll") for (int m = 0; m < 4; ++m) \
      _Pragma("unroll") for (int n = 0; n < 2; ++n) { \
        acc[(mh)*4+m][(pr)*2+n] = __builtin_amdgcn_mfma_f32_16x16x32_bf16( \
            a[m][0], breg[n][0], acc[(mh)*4+m][(pr)*2+n], 0, 0, 0); \
        acc[(mh)*4+m][(pr)*2+n] = __builtin_amdgcn_mfma_f32_16x16x32_bf16( \
            a[m][1], breg[n][1], acc[(mh)*4+m][(pr)*2+n], 0, 0, 0); \
      } } while (0)

  // prologue: stage tile0 (4 halves) + tile1 {B0,B1,A0}; wait tile0 landed
  for (int j = 0; j < 7; ++j) stage_hh(sm, pA, pB, tid, j);
  asm volatile("s_waitcnt vmcnt(6)" ::: "memory"); SB;
  BARR; SB;

#define TILE(t, d) do { \
    const char* aB = sm + (d) * 65536 + wr * 16384; \
    const char* bB = sm + (d) * 65536 + 32768 + (wc >> 1) * 16384 + (wc & 1) * 8192; \
    /* ph0: A(mh0) + B(n2,3) reads; stage A1 of t+1 (other buf); MFMA quad (0,1) */ \
    LDA(0); LDB(b23, 1); \
    stage_hh(sm, pA, pB, tid, 4 * (t) + 7); \
    SB; BARR; WLG; \
    __builtin_amdgcn_s_setprio(1); MF(0, 1, b23); __builtin_amdgcn_s_setprio(0); \
    SB; BARR; SB; \
    /* ph1: B(n0,1) reads (LAST B-region reads); no stage; MFMA quad (0,0) */ \
    LDB(b01, 0); \
    SB; BARR; WLG; \
    __builtin_amdgcn_s_setprio(1); MF(0, 0, b01); __builtin_amdgcn_s_setprio(0); \
    SB; BARR; SB; \
    /* ph2: A(mh1) reads (LAST A-region reads); stage B0 of t+2; MFMA quad (1,0) */ \
    LDA(1); \
    stage_hh(sm, pA, pB, tid, 4 * (t) + 8); \
    SB; BARR; WLG; \
    __builtin_amdgcn_s_setprio(1); MF(1, 0, b01); __builtin_amdgcn_s_setprio(0); \
    SB; BARR; SB; \
    /* ph3: no reads; stage B1 + A0 of t+2; MFMA quad (1,1); tile-boundary vmcnt */ \
    stage_hh(sm, pA, pB, tid, 4 * (t) + 9); \
    stage_hh(sm, pA, pB, tid, 4 * (t) + 10); \
    SB; BARR; SB; \
    __builtin_amdgcn_s_setprio(1); MF(1, 1, b23); __builtin_amdgcn_s_setprio(0); \
    SB; \
    if ((t) < 6) { asm volatile("s_waitcnt vmcnt(6)" ::: "memory"); } \
    else         { asm volatile("s_waitcnt vmcnt(0)" ::: "memory"); } \
    SB; BARR; SB; \
  } while (0)

  for (int i = 0; i < 4; ++i) {
    int t0 = 2 * i;
    TILE(t0, 0);
    TILE(t0 + 1, 1);
  }

  // ---- epilogue: per-row stripe max (128-col granularity) via LDS reuse
  float (*wmax)[256] = (float(*)[256])sm;  // [wc][row-in-block], 4 KiB
#pragma unroll
  for (int m = 0; m < 8; ++m) {
    float rm[4];
#pragma unroll
    for (int r = 0; r < 4; ++r)
      rm[r] = fmaxf(fmaxf(acc[m][0][r], acc[m][1][r]), fmaxf(acc[m][2][r], acc[m][3][r]));
#pragma unroll
    for (int s = 1; s < 16; s <<= 1)
#pragma unroll
      for (int r = 0; r < 4; ++r) rm[r] = fmaxf(rm[r], __shfl_xor(rm[r], s, 64));
    if (row16 == 0)
#pragma unroll
      for (int r = 0; r < 4; ++r) wmax[wc][wr * 128 + m * 16 + quad * 4 + r] = rm[r];
  }

  // dist write: D layout col = lane&15, row = quad*4 + reg (verified convention)
#pragma unroll
  for (int m = 0; m < 8; ++m) {
#pragma unroll
    for (int r = 0; r < 4; ++r) {
      size_t grow = (size_t)(rowBase + wr * 128 + m * 16 + quad * 4 + r);
      float* dp = dist + grow * C_CODES + colBase + wc * 64 + row16;
#pragma unroll
      for (int n = 0; n < 4; ++n) dp[n * 16] = acc[m][n][r];
    }
  }

  __syncthreads();
  if (tid < 256) {
    float v = fmaxf(wmax[0][tid], wmax[1][tid]);
    tilemax[(size_t)(rowBase + tid) * 64 + cb * 2] = v;
  } else {
    int rr = tid - 256;
    float v = fmaxf(wmax[2][rr], wmax[3][rr]);
    tilemax[(size_t)(rowBase + rr) * 64 + cb * 2 + 1] = v;
  }
}

// ---- Kernel 4: per row — exact fp32 argmax among candidates within EPS of the
// bf16-dist row max. One WAVE per row, fully shuffle/ballot-based.
#define EPS 0.01f

__global__ __launch_bounds__(256) void refine(
    const float* __restrict__ x, const float* __restrict__ en,
    const float* __restrict__ xnorm, const float* __restrict__ tilemax,
    const float* __restrict__ dist, float* __restrict__ out) {
  int wave = threadIdx.x >> 6, lane = threadIdx.x & 63;
  int r = blockIdx.x * 4 + wave;

  float tmv = tilemax[(size_t)r * 64 + lane];
  float m = tmv;
#pragma unroll
  for (int s = 1; s < 64; s <<= 1) m = fmaxf(m, __shfl_xor(m, s, 64));
  float T = m - EPS;

  const float* xr = x + (size_t)r * DIM;
  float4 xv0 = ((const float4*)xr)[lane * 2];
  float4 xv1 = ((const float4*)xr)[lane * 2 + 1];
  float nrm = xnorm[r];

  const float* drow = dist + (size_t)r * C_CODES;
  float bv = -3.0e38f;
  int bi = 0x7fffffff;

  unsigned long long smask = __ballot(tmv >= T);
  while (smask) {
    int cbB = __builtin_ctzll(smask);
    smask &= smask - 1;
    int base = cbB * 128;
    float v0 = drow[base + lane];
    float v1 = drow[base + 64 + lane];
    unsigned long long b0 = __ballot(v0 >= T);
    unsigned long long b1 = __ballot(v1 >= T);
    while (b0 | b1) {
      int c;
      if (b0) {
        int l = __builtin_ctzll(b0); b0 &= b0 - 1; c = base + l;
      } else {
        int l = __builtin_ctzll(b1); b1 &= b1 - 1; c = base + 64 + l;
      }
      const float* er = en + (size_t)c * DIM;
      float4 e0 = ((const float4*)er)[lane * 2];
      float4 e1 = ((const float4*)er)[lane * 2 + 1];
      float d = xv0.x * e0.x + xv0.y * e0.y + xv0.z * e0.z + xv0.w * e0.w +
                xv1.x * e1.x + xv1.y * e1.y + xv1.z * e1.z + xv1.w * e1.w;
#pragma unroll
      for (int s = 1; s < 64; s <<= 1) d += __shfl_xor(d, s, 64);
      float v = d / nrm;
      if (v > bv || (v == bv && c < bi)) { bv = v; bi = c; }
    }
  }

  if (lane == 0) out[I_OFS + r] = (float)bi;
  const float* eb = en + (size_t)bi * DIM;
  float4 q0 = ((const float4*)eb)[lane * 2];
  float4 q1 = ((const float4*)eb)[lane * 2 + 1];
  float* orow = out + (size_t)r * DIM;
  ((float4*)orow)[lane * 2] = q0;
  ((float4*)orow)[lane * 2 + 1] = q1;
}

extern "C" void kernel_launch(void* const* d_in, const int* in_sizes, int n_in,
                              void* d_out, int out_size, void* d_ws, size_t ws_size,
                              hipStream_t stream) {
  const float* x = (const float*)d_in[0];      // [16384, 512]
  const float* embed = (const float*)d_in[1];  // [8192, 512]
  float* out = (float*)d_out;
  char* ws = (char*)d_ws;
  // workspace layout (46.2 MB total)
  bf16* enb = (bf16*)(ws);                       //  8,388,608 B
  bf16* xnb = (bf16*)(ws + 8388608);             // 16,777,216 B
  float* en = (float*)(ws + 25165824);           // 16,777,216 B
  float* xnorm = (float*)(ws + 41943040);        //     65,536 B
  float* tilemax = (float*)(ws + 42008576);      //  4,194,304 B

  hipLaunchKernelGGL(norm_embed, dim3(C_CODES / 4), dim3(256), 0, stream, embed, en, enb);
  hipLaunchKernelGGL(norm_x, dim3(N_ROWS / 4), dim3(256), 0, stream, x, xnb, xnorm);
  hipLaunchKernelGGL(gemm_dist, dim3(2048), dim3(512), 0, stream,
                     xnb, enb, out + D_OFS, tilemax);
  hipLaunchKernelGGL(refine, dim3(N_ROWS / 4), dim3(256), 0, stream,
                     x, en, xnorm, tilemax, out + D_OFS, out);
}